// Round 6
// baseline (335.435 us; speedup 1.0000x reference)
//
#include <hip/hip_runtime.h>

typedef _Float16 half8 __attribute__((ext_vector_type(8)));
typedef float    f32x16 __attribute__((ext_vector_type(16)));

constexpr int kH = 16;    // heads
constexpr int kO = 1024;  // codebook options
constexpr int kA = 128;   // head size
constexpr int kBS = 4096; // B*S positions
constexpr int PCHUNK = 256;          // positions per block
constexpr int XT = PCHUNK / 32;      // 8 x-tiles per block
constexpr int OPW = 64;              // options per wave (2 MFMA row-tiles)
constexpr int OCHUNK = 4 * OPW;      // 256 options per block (4 waves)

// fp32 -> fp16 hi/lo split of 8 consecutive floats (same math as before)
__device__ __forceinline__ void cvt44(float4 v0, float4 v1, half8& hi, half8& lo) {
    float va[8] = { v0.x, v0.y, v0.z, v0.w, v1.x, v1.y, v1.z, v1.w };
#pragma unroll
    for (int j = 0; j < 8; ++j) {
        _Float16 hj = (_Float16)va[j];
        hi[j] = hj;
        lo[j] = (_Float16)(va[j] - (float)hj);
    }
}

// ---- Pass 1: W-stationary scoring, deferred argmax merge. ----
// Block = (head, 256-option chunk, 256 positions). Each wave pins 64 options
// of hi/lo-split W in 128 VGPRs. x streams as 32-position tiles through
// double-buffered LDS (cooperative convert, 1 barrier/tile). Inner loop:
// 24 ds_read_b128 + 48 MFMA (2 chains) — zero vmem on the critical path.
// Argmax merge (G12): per-iter keys go to LDS (double-buffered), wave 0
// pre-reduces 4 waves -> 1 key/position after the existing barrier, and ONE
// pipelined atomicMax flush per thread at kernel end (4-deep contention,
// single vmcnt drain) — R5's in-loop 16-deep contended atomic + per-iter
// vmcnt(0)-before-barrier drain was the 82%-idle stall.
__launch_bounds__(256, 4)
__global__ void vq_score(const float* __restrict__ x,
                         const float* __restrict__ w,
                         unsigned long long* __restrict__ keys) {
    __shared__ ushort xfrag[2][2][8][512];          // [buf][plane][ks][lane*8] = 32 KiB
    __shared__ unsigned long long keybuf[2][4][32]; // [buf][wv][pos31] = 2 KiB
    __shared__ unsigned long long pending[XT][32];  // final key per (tile,pos) = 2 KiB

    const int tid  = threadIdx.x;
    const int lane = tid & 63;
    const int wv   = tid >> 6;      // 0..3
    const int bid  = blockIdx.x;    // 1024 blocks = 8 xcd x 2 h x 4 oc x 16 pc
    // XCD-aware: XCD (bid&7) touches only heads {2x,2x+1}
    const int xcd = bid & 7;
    const int r   = bid >> 3;               // 0..127
    const int h   = (xcd << 1) | (r & 1);
    const int oc  = (r >> 1) & 3;
    const int pc  = r >> 3;                 // 0..15
    const int p0  = pc * PCHUNK;
    const int obase = oc * OCHUNK + wv * OPW;

    const int l31  = lane & 31;
    const int half = lane >> 5;

    // ---- W prologue: 64 options -> wh0/wl0 (opts +0..31), wh1/wl1 (+32..63)
    const float* wb = w + (h * kO + obase + l31) * kA + half * 8;
    half8 wh0[8], wl0[8], wh1[8], wl1[8];
#pragma unroll
    for (int ks = 0; ks < 8; ++ks) {
        float4 a0 = *(const float4*)(wb + ks * 16);
        float4 a1 = *(const float4*)(wb + ks * 16 + 4);
        cvt44(a0, a1, wh0[ks], wl0[ks]);
        float4 b0 = *(const float4*)(wb + 32 * kA + ks * 16);
        float4 b1 = *(const float4*)(wb + 32 * kA + ks * 16 + 4);
        cvt44(b0, b1, wh1[ks], wl1[ks]);
    }

    // ---- cooperative x staging: thread t converts slots t and t+256
    // slot s: ks = s>>6, ls = s&63 -> x[pos = p0+xt*32+(ls&31)][ks*16+(ls>>5)*8 ..+8]
    const int ls  = tid & 63;
    const int ks0 = tid >> 6;       // 0..3 (second slot: ks0+4)
    const float* xsrc = x + ((p0 + (ls & 31)) * kH + h) * kA + ks0 * 16 + (ls >> 5) * 8;
    const int xtile_stride = 32 * kH * kA;   // 32 positions, in floats

    // stage+convert tile 0 into buf 0
    {
        float4 n0a = *(const float4*)(xsrc);
        float4 n0b = *(const float4*)(xsrc + 4);
        float4 n1a = *(const float4*)(xsrc + 64);
        float4 n1b = *(const float4*)(xsrc + 68);
        half8 hi, lo;
        cvt44(n0a, n0b, hi, lo);
        *(half8*)&xfrag[0][0][ks0][ls * 8] = hi;
        *(half8*)&xfrag[0][1][ks0][ls * 8] = lo;
        cvt44(n1a, n1b, hi, lo);
        *(half8*)&xfrag[0][0][ks0 + 4][ls * 8] = hi;
        *(half8*)&xfrag[0][1][ks0 + 4][ls * 8] = lo;
    }
    __syncthreads();

    for (int xt = 0; xt < XT; ++xt) {
        const int cur = xt & 1;

        // issue next x-tile's global loads EARLY (consumed after MFMAs)
        float4 n0a, n0b, n1a, n1b;
        if (xt + 1 < XT) {
            const float* np = xsrc + (xt + 1) * xtile_stride;
            n0a = *(const float4*)(np);
            n0b = *(const float4*)(np + 4);
            n1a = *(const float4*)(np + 64);
            n1b = *(const float4*)(np + 68);
        }

        // compute: 2 chains, per-chain order = wh*xh, wh*xl, wl*xh (ks 0..7)
        f32x16 acc0 = {}, acc1 = {};
#pragma unroll
        for (int ks = 0; ks < 8; ++ks) {
            half8 xh = *(const half8*)&xfrag[cur][0][ks][lane * 8];
            acc0 = __builtin_amdgcn_mfma_f32_32x32x16_f16(wh0[ks], xh, acc0, 0, 0, 0);
            acc1 = __builtin_amdgcn_mfma_f32_32x32x16_f16(wh1[ks], xh, acc1, 0, 0, 0);
        }
#pragma unroll
        for (int ks = 0; ks < 8; ++ks) {
            half8 xl = *(const half8*)&xfrag[cur][1][ks][lane * 8];
            acc0 = __builtin_amdgcn_mfma_f32_32x32x16_f16(wh0[ks], xl, acc0, 0, 0, 0);
            acc1 = __builtin_amdgcn_mfma_f32_32x32x16_f16(wh1[ks], xl, acc1, 0, 0, 0);
        }
#pragma unroll
        for (int ks = 0; ks < 8; ++ks) {
            half8 xh = *(const half8*)&xfrag[cur][0][ks][lane * 8];
            acc0 = __builtin_amdgcn_mfma_f32_32x32x16_f16(wl0[ks], xh, acc0, 0, 0, 0);
            acc1 = __builtin_amdgcn_mfma_f32_32x32x16_f16(wl1[ks], xh, acc1, 0, 0, 0);
        }

        // convert + write next tile into the other buffer (before barrier)
        if (xt + 1 < XT) {
            const int nb = cur ^ 1;
            half8 hi, lo;
            cvt44(n0a, n0b, hi, lo);
            *(half8*)&xfrag[nb][0][ks0][ls * 8] = hi;
            *(half8*)&xfrag[nb][1][ks0][ls * 8] = lo;
            cvt44(n1a, n1b, hi, lo);
            *(half8*)&xfrag[nb][0][ks0 + 4][ls * 8] = hi;
            *(half8*)&xfrag[nb][1][ks0 + 4][ls * 8] = lo;
        }

        // fold: per lane, best over this wave's 64 options for position l31
        // C layout: pos = lane&31, opt_row = (r&3)+8*(r>>2)+4*(lane>>5)
        float lv0 = acc0[0]; int lr0 = 0;
#pragma unroll
        for (int rr = 1; rr < 16; ++rr)
            if (acc0[rr] > lv0) { lv0 = acc0[rr]; lr0 = rr; }   // rowmap ascending
        float lv1 = acc1[0]; int lr1 = 0;
#pragma unroll
        for (int rr = 1; rr < 16; ++rr)
            if (acc1[rr] > lv1) { lv1 = acc1[rr]; lr1 = rr; }

        float bv = lv0;
        int   bo = obase + ((lr0 & 3) + 8 * (lr0 >> 2) + 4 * half);
        int   o1 = obase + 32 + ((lr1 & 3) + 8 * (lr1 >> 2) + 4 * half);
        if (lv1 > bv) { bv = lv1; bo = o1; }                    // tie -> chain0

        float om = __shfl_xor(bv, 32, 64);
        int   oi = __shfl_xor(bo, 32, 64);
        if (om > bv || (om == bv && oi < bo)) { bv = om; bo = oi; }

        if (half == 0) {
            uint32_t vb   = __builtin_bit_cast(uint32_t, bv);
            uint32_t mono = (vb & 0x80000000u) ? ~vb : (vb | 0x80000000u);
            keybuf[cur][wv][l31] =
                ((unsigned long long)mono << 32) | (uint32_t)~(uint32_t)bo;
        }

        __syncthreads();   // next xfrag staged + keybuf[cur] complete

        // wave 0 pre-reduces this tile's 4 wave-keys (keybuf[cur] is not
        // rewritten until fold(xt+2), which is after the NEXT barrier)
        if (tid < 32) {
            unsigned long long k0 = keybuf[cur][0][tid];
            unsigned long long k1 = keybuf[cur][1][tid];
            unsigned long long k2 = keybuf[cur][2][tid];
            unsigned long long k3 = keybuf[cur][3][tid];
            unsigned long long ka = k0 > k1 ? k0 : k1;
            unsigned long long kb = k2 > k3 ? k2 : k3;
            pending[xt][tid] = ka > kb ? ka : kb;   // ties: bigger ~bo = smaller o
        }
    }

    __syncthreads();   // pending[] complete

    // flush: XT*32 = 256 keys, exactly 1 atomic per thread, pipelined, 1 drain
    {
        int xt = tid >> 5, row = tid & 31;
        atomicMax(&keys[(p0 + xt * 32 + row) * kH + h], pending[xt][row]);
    }
}

// ---- Pass 2: decode keys + gather codebook rows ----
__launch_bounds__(256)
__global__ void vq_gather(const unsigned long long* __restrict__ keys,
                          const float* __restrict__ cb,
                          float* __restrict__ out) {
    const int total = kBS * kH * 32;   // float4s
    for (int i = blockIdx.x * blockDim.x + threadIdx.x; i < total;
         i += gridDim.x * blockDim.x) {
        int row = i >> 5, ch = i & 31;
        unsigned long long k = keys[row];
        int o = (int)(~(uint32_t)k) & (kO - 1);
        int hh = row & (kH - 1);
        float4 v = *(const float4*)(cb + (hh * kO + o) * kA + ch * 4);
        *(float4*)(out + row * kA + ch * 4) = v;
    }
}

extern "C" void kernel_launch(void* const* d_in, const int* in_sizes, int n_in,
                              void* d_out, int out_size, void* d_ws, size_t ws_size,
                              hipStream_t stream) {
    const float* x  = (const float*)d_in[0];   // [4096,16,128] fp32
    const float* w  = (const float*)d_in[1];   // [16,1024,128] fp32
    const float* cb = (const float*)d_in[2];   // [16,1024,128] fp32
    // d_in[3] = temperature: forward value is temperature-independent
    float* out = (float*)d_out;                // [4096,16,128] fp32

    unsigned long long* keys = (unsigned long long*)d_ws;   // 512 KiB argmax keys

    hipMemsetAsync(keys, 0, (size_t)kBS * kH * 8, stream);  // all logits' keys > 0
    vq_score<<<dim3(1024), dim3(256), 0, stream>>>(x, w, keys);
    vq_gather<<<dim3(2048), dim3(256), 0, stream>>>(keys, cb, out);
}

// Round 7
// 150.807 us; speedup vs baseline: 2.2243x; 2.2243x over previous
//
#include <hip/hip_runtime.h>

typedef _Float16 half8 __attribute__((ext_vector_type(8)));
typedef float    f32x16 __attribute__((ext_vector_type(16)));

constexpr int kH = 16;    // heads
constexpr int kO = 1024;  // codebook options
constexpr int kA = 128;   // head size
constexpr int kBS = 4096; // B*S positions
constexpr int PCHUNK = 512;          // positions per block
constexpr int XT = PCHUNK / 32;      // 16 x-tiles per block
constexpr int OPW = 64;              // options per wave (2 MFMA row-tiles)
constexpr int OCHUNK = 4 * OPW;      // 256 options per block (4 waves)

// fp32 -> fp16 hi/lo split of 8 consecutive floats (same math as before)
__device__ __forceinline__ void cvt44(float4 v0, float4 v1, half8& hi, half8& lo) {
    float va[8] = { v0.x, v0.y, v0.z, v0.w, v1.x, v1.y, v1.z, v1.w };
#pragma unroll
    for (int j = 0; j < 8; ++j) {
        _Float16 hj = (_Float16)va[j];
        hi[j] = hj;
        lo[j] = (_Float16)(va[j] - (float)hj);
    }
}

// ---- Pass 1: W-stationary scoring, deferred argmax merge. ----
// Block = (head, 256-option chunk, 512 positions). Each wave pins 64 options
// of hi/lo-split W in registers (R5-proven envelope: launch_bounds(256,2),
// VGPR 108, no spill — R6's (256,4) forced a 603-MB scratch catastrophe).
// x streams as 32-position tiles through double-buffered LDS. Inner loop:
// 24 ds_read_b128 + 48 MFMA (2 chains) — zero vmem on the critical path.
// Argmax merge (G12): per-iter keys -> LDS keybuf (double-buffered); wave 0
// pre-reduces 4 waves -> 1 key/position after the existing barrier; ONE
// pipelined atomicMax flush at kernel end (4-deep contention, single drain).
// R5's in-loop 16-deep contended atomic + per-iter vmcnt(0) drain was the
// 82%-idle stall this removes.
__launch_bounds__(256, 2)
__global__ void vq_score(const float* __restrict__ x,
                         const float* __restrict__ w,
                         unsigned long long* __restrict__ keys) {
    __shared__ ushort xfrag[2][2][8][512];          // [buf][plane][ks][lane*8] = 32 KiB
    __shared__ unsigned long long keybuf[2][4][32]; // [buf][wv][pos31] = 2 KiB
    __shared__ unsigned long long pending[XT][32];  // final key per (tile,pos) = 4 KiB

    const int tid  = threadIdx.x;
    const int lane = tid & 63;
    const int wv   = tid >> 6;      // 0..3
    const int bid  = blockIdx.x;    // 512 blocks = 8 xcd x 2 h x 4 oc x 8 pc
    // XCD-aware: XCD (bid&7) touches only heads {2x,2x+1}
    const int xcd = bid & 7;
    const int r   = bid >> 3;               // 0..63
    const int h   = (xcd << 1) | (r & 1);
    const int oc  = (r >> 1) & 3;
    const int pc  = r >> 3;                 // 0..7
    const int p0  = pc * PCHUNK;
    const int obase = oc * OCHUNK + wv * OPW;

    const int l31  = lane & 31;
    const int half = lane >> 5;

    // ---- W prologue: 64 options -> wh0/wl0 (opts +0..31), wh1/wl1 (+32..63)
    const float* wb = w + (h * kO + obase + l31) * kA + half * 8;
    half8 wh0[8], wl0[8], wh1[8], wl1[8];
#pragma unroll
    for (int ks = 0; ks < 8; ++ks) {
        float4 a0 = *(const float4*)(wb + ks * 16);
        float4 a1 = *(const float4*)(wb + ks * 16 + 4);
        cvt44(a0, a1, wh0[ks], wl0[ks]);
        float4 b0 = *(const float4*)(wb + 32 * kA + ks * 16);
        float4 b1 = *(const float4*)(wb + 32 * kA + ks * 16 + 4);
        cvt44(b0, b1, wh1[ks], wl1[ks]);
    }

    // ---- cooperative x staging: thread t converts slots t and t+256
    // slot s: ks = s>>6, ls = s&63 -> x[pos = p0+xt*32+(ls&31)][ks*16+(ls>>5)*8 ..+8]
    const int ls  = tid & 63;
    const int ks0 = tid >> 6;       // 0..3 (second slot: ks0+4)
    const float* xsrc = x + ((p0 + (ls & 31)) * kH + h) * kA + ks0 * 16 + (ls >> 5) * 8;
    const int xtile_stride = 32 * kH * kA;   // 32 positions, in floats

    // stage+convert tile 0 into buf 0
    {
        float4 n0a = *(const float4*)(xsrc);
        float4 n0b = *(const float4*)(xsrc + 4);
        float4 n1a = *(const float4*)(xsrc + 64);
        float4 n1b = *(const float4*)(xsrc + 68);
        half8 hi, lo;
        cvt44(n0a, n0b, hi, lo);
        *(half8*)&xfrag[0][0][ks0][ls * 8] = hi;
        *(half8*)&xfrag[0][1][ks0][ls * 8] = lo;
        cvt44(n1a, n1b, hi, lo);
        *(half8*)&xfrag[0][0][ks0 + 4][ls * 8] = hi;
        *(half8*)&xfrag[0][1][ks0 + 4][ls * 8] = lo;
    }
    __syncthreads();

    for (int xt = 0; xt < XT; ++xt) {
        const int cur = xt & 1;

        // issue next x-tile's global loads EARLY (consumed after MFMAs)
        float4 n0a, n0b, n1a, n1b;
        if (xt + 1 < XT) {
            const float* np = xsrc + (xt + 1) * xtile_stride;
            n0a = *(const float4*)(np);
            n0b = *(const float4*)(np + 4);
            n1a = *(const float4*)(np + 64);
            n1b = *(const float4*)(np + 68);
        }

        // compute: 2 chains, per-chain order = wh*xh, wh*xl, wl*xh (ks 0..7)
        f32x16 acc0 = {}, acc1 = {};
#pragma unroll
        for (int ks = 0; ks < 8; ++ks) {
            half8 xh = *(const half8*)&xfrag[cur][0][ks][lane * 8];
            acc0 = __builtin_amdgcn_mfma_f32_32x32x16_f16(wh0[ks], xh, acc0, 0, 0, 0);
            acc1 = __builtin_amdgcn_mfma_f32_32x32x16_f16(wh1[ks], xh, acc1, 0, 0, 0);
        }
#pragma unroll
        for (int ks = 0; ks < 8; ++ks) {
            half8 xl = *(const half8*)&xfrag[cur][1][ks][lane * 8];
            acc0 = __builtin_amdgcn_mfma_f32_32x32x16_f16(wh0[ks], xl, acc0, 0, 0, 0);
            acc1 = __builtin_amdgcn_mfma_f32_32x32x16_f16(wh1[ks], xl, acc1, 0, 0, 0);
        }
#pragma unroll
        for (int ks = 0; ks < 8; ++ks) {
            half8 xh = *(const half8*)&xfrag[cur][0][ks][lane * 8];
            acc0 = __builtin_amdgcn_mfma_f32_32x32x16_f16(wl0[ks], xh, acc0, 0, 0, 0);
            acc1 = __builtin_amdgcn_mfma_f32_32x32x16_f16(wl1[ks], xh, acc1, 0, 0, 0);
        }

        // convert + write next tile into the other buffer (before barrier)
        if (xt + 1 < XT) {
            const int nb = cur ^ 1;
            half8 hi, lo;
            cvt44(n0a, n0b, hi, lo);
            *(half8*)&xfrag[nb][0][ks0][ls * 8] = hi;
            *(half8*)&xfrag[nb][1][ks0][ls * 8] = lo;
            cvt44(n1a, n1b, hi, lo);
            *(half8*)&xfrag[nb][0][ks0 + 4][ls * 8] = hi;
            *(half8*)&xfrag[nb][1][ks0 + 4][ls * 8] = lo;
        }

        // fold: per lane, best over this wave's 64 options for position l31
        // C layout: pos = lane&31, opt_row = (r&3)+8*(r>>2)+4*(lane>>5)
        float lv0 = acc0[0]; int lr0 = 0;
#pragma unroll
        for (int rr = 1; rr < 16; ++rr)
            if (acc0[rr] > lv0) { lv0 = acc0[rr]; lr0 = rr; }   // rowmap ascending
        float lv1 = acc1[0]; int lr1 = 0;
#pragma unroll
        for (int rr = 1; rr < 16; ++rr)
            if (acc1[rr] > lv1) { lv1 = acc1[rr]; lr1 = rr; }

        float bv = lv0;
        int   bo = obase + ((lr0 & 3) + 8 * (lr0 >> 2) + 4 * half);
        int   o1 = obase + 32 + ((lr1 & 3) + 8 * (lr1 >> 2) + 4 * half);
        if (lv1 > bv) { bv = lv1; bo = o1; }                    // tie -> chain0

        float om = __shfl_xor(bv, 32, 64);
        int   oi = __shfl_xor(bo, 32, 64);
        if (om > bv || (om == bv && oi < bo)) { bv = om; bo = oi; }

        if (half == 0) {
            uint32_t vb   = __builtin_bit_cast(uint32_t, bv);
            uint32_t mono = (vb & 0x80000000u) ? ~vb : (vb | 0x80000000u);
            keybuf[cur][wv][l31] =
                ((unsigned long long)mono << 32) | (uint32_t)~(uint32_t)bo;
        }

        __syncthreads();   // next xfrag staged + keybuf[cur] complete

        // wave 0 pre-reduces this tile's 4 wave-keys. Safe: keybuf[cur] is
        // next rewritten only in fold(xt+2), which is behind the next barrier.
        if (tid < 32) {
            unsigned long long k0 = keybuf[cur][0][tid];
            unsigned long long k1 = keybuf[cur][1][tid];
            unsigned long long k2 = keybuf[cur][2][tid];
            unsigned long long k3 = keybuf[cur][3][tid];
            unsigned long long ka = k0 > k1 ? k0 : k1;
            unsigned long long kb = k2 > k3 ? k2 : k3;
            pending[xt][tid] = ka > kb ? ka : kb;   // ties: bigger ~bo = smaller o
        }
    }

    __syncthreads();   // pending[] complete

    // flush: XT*32 = 512 keys, 2 atomics per thread, pipelined, single drain
    for (int i = tid; i < XT * 32; i += 256) {
        int xt = i >> 5, row = i & 31;
        atomicMax(&keys[(p0 + xt * 32 + row) * kH + h], pending[xt][row]);
    }
}

// ---- Pass 2: decode keys + gather codebook rows ----
__launch_bounds__(256)
__global__ void vq_gather(const unsigned long long* __restrict__ keys,
                          const float* __restrict__ cb,
                          float* __restrict__ out) {
    const int total = kBS * kH * 32;   // float4s
    for (int i = blockIdx.x * blockDim.x + threadIdx.x; i < total;
         i += gridDim.x * blockDim.x) {
        int row = i >> 5, ch = i & 31;
        unsigned long long k = keys[row];
        int o = (int)(~(uint32_t)k) & (kO - 1);
        int hh = row & (kH - 1);
        float4 v = *(const float4*)(cb + (hh * kO + o) * kA + ch * 4);
        *(float4*)(out + row * kA + ch * 4) = v;
    }
}

extern "C" void kernel_launch(void* const* d_in, const int* in_sizes, int n_in,
                              void* d_out, int out_size, void* d_ws, size_t ws_size,
                              hipStream_t stream) {
    const float* x  = (const float*)d_in[0];   // [4096,16,128] fp32
    const float* w  = (const float*)d_in[1];   // [16,1024,128] fp32
    const float* cb = (const float*)d_in[2];   // [16,1024,128] fp32
    // d_in[3] = temperature: forward value is temperature-independent
    float* out = (float*)d_out;                // [4096,16,128] fp32

    unsigned long long* keys = (unsigned long long*)d_ws;   // 512 KiB argmax keys

    hipMemsetAsync(keys, 0, (size_t)kBS * kH * 8, stream);  // all logits' keys > 0
    vq_score<<<dim3(512),  dim3(256), 0, stream>>>(x, w, keys);
    vq_gather<<<dim3(2048), dim3(256), 0, stream>>>(keys, cb, out);
}